// Round 2
// baseline (468.044 us; speedup 1.0000x reference)
//
#include <hip/hip_runtime.h>
#include <math.h>

constexpr int D = 64;
constexpr int H = 4;

// ---------------------------------------------------------------------------
// R21: scatter split into two L2-local phases.  Old scatter wrote 4B to a
// random line per edge -> 53 MB writeback (16x amplification), 52us.
// Phase A (scatter_bin): append packed (rel8|col24) into 256-node buckets;
// bucket frontier = 391 hot lines -> full-line writebacks (~3.2MB logical).
// Bucket bases = off[b*256], emitted by block_scan into bcur for free.
// Phase B (bucket_sort): block per bucket; coalesced read, LDS atomic
// placement vs per-node off, staged 16KB LDS buffer, coalesced sc write.
// Fallback to global-atomic path if a bucket > 4096 edges (never here).
// R20: aggregate 4 edges/wave-step (lane=dim-quad d=l&15, slot es=l>>4).
// Layouts (verified learn_hip m89/m120): A[m=lane&15][k=(lane>>4)*8+j],
// B[k=(lane>>4)*8+j][n=lane&15], C/D col=lane&15 row=(lane>>4)*4+reg.
// ---------------------------------------------------------------------------

typedef __attribute__((ext_vector_type(8))) short bf16x8;
typedef __attribute__((ext_vector_type(4))) float f32x4;

__device__ __forceinline__ unsigned short f32_to_bf16(float f) {
    const unsigned int u = __float_as_uint(f);
    return (unsigned short)((u + 0x7FFFu + ((u >> 16) & 1u)) >> 16);  // RNE
}
__device__ __forceinline__ float bf16_to_f32(unsigned short h) {
    return __uint_as_float(((unsigned int)h) << 16);
}
__device__ __forceinline__ float bf16lo_f32(unsigned int w) {   // bits 0-15
    return __uint_as_float(w << 16);
}
__device__ __forceinline__ float bf16hi_f32(unsigned int w) {   // bits 16-31
    return __uint_as_float(w & 0xFFFF0000u);
}

// ---------------------------------------------------------------------------
// Kernel 0: pre-split W into hi/lo MFMA B-fragment order with PERMUTED column
// map: fragment (mt, ct, ks, lane l, j) <- W_mt[ks*32+(l>>4)*8+j][4*(l&15)+ct]
// so MFMA acc[mt][ct] at lane m holds ORIGINAL output col 4m+ct.
// ---------------------------------------------------------------------------
__global__ __launch_bounds__(256) void prep_w_kernel(
    const float* __restrict__ Wq, const float* __restrict__ Wk,
    const float* __restrict__ Wv,
    unsigned short* __restrict__ WfH, unsigned short* __restrict__ WfL) {
    const float* W[3] = {Wq, Wk, Wv};
    for (int idx = blockIdx.x * 256 + threadIdx.x; idx < 3 * 4 * 2 * 64 * 8;
         idx += gridDim.x * 256) {
        const int j  = idx & 7;
        const int l  = (idx >> 3) & 63;
        const int ks = (idx >> 9) & 1;
        const int ct = (idx >> 10) & 3;
        const int mt = idx >> 12;
        const int krow = ks * 32 + (l >> 4) * 8 + j;
        const int col  = 4 * (l & 15) + ct;          // permuted column map
        const float w  = W[mt][krow * 64 + col];
        const unsigned short h = f32_to_bf16(w);
        WfH[idx] = h;
        WfL[idx] = f32_to_bf16(w - bf16_to_f32(h));
    }
}

// ---------------------------------------------------------------------------
// Kernel 1: QKV projection via split-precision MFMA (Ah*Bh + Ah*Bl + Al*Bh).
// Block = 4 waves; wave = 16 nodes.  Wf hi/lo staged in LDS (48 KB).
// Outputs: Q fp32 (dwordx4 per lane), KVP uint2 pairs (dwordx4 per lane).
// ---------------------------------------------------------------------------
__global__ __launch_bounds__(256) void qkv_kernel(
    const float* __restrict__ emb,
    const unsigned short* __restrict__ WfH,
    const unsigned short* __restrict__ WfL,
    int N, float* __restrict__ Q, unsigned int* __restrict__ KVP) {
    __shared__ unsigned short sH[12288];   // 24 KB
    __shared__ unsigned short sL[12288];   // 24 KB
    const int tid = threadIdx.x;

    {
        const uint4* gh = (const uint4*)WfH;
        const uint4* gl = (const uint4*)WfL;
        uint4* shh = (uint4*)sH;
        uint4* sll = (uint4*)sL;
        for (int k = tid; k < 1536; k += 256) {
            shh[k] = gh[k];
            sll[k] = gl[k];
        }
    }
    __syncthreads();

    const int wv = tid >> 6;
    const int l  = tid & 63;
    const int qd = l >> 4;              // quad 0..3
    const int m  = l & 15;
    const int n0 = blockIdx.x * 64 + wv * 16;

    // A fragments, split hi/lo: k = ks*32 + qd*8 + j
    bf16x8 aH[2], aL[2];
    {
        int node = n0 + m;
        if (node >= N) node = N - 1;
        const float4* ep = (const float4*)(emb + (size_t)node * 64);
#pragma unroll
        for (int ks = 0; ks < 2; ++ks) {
            const float4 a0 = ep[ks * 8 + qd * 2 + 0];
            const float4 a1 = ep[ks * 8 + qd * 2 + 1];
            const float f[8] = {a0.x, a0.y, a0.z, a0.w, a1.x, a1.y, a1.z, a1.w};
            bf16x8 fh, fl;
#pragma unroll
            for (int j = 0; j < 8; ++j) {
                const unsigned short h = f32_to_bf16(f[j]);
                fh[j] = (short)h;
                fl[j] = (short)f32_to_bf16(f[j] - bf16_to_f32(h));
            }
            aH[ks] = fh;
            aL[ks] = fl;
        }
    }

    f32x4 acc[3][4];
#pragma unroll
    for (int mt = 0; mt < 3; ++mt)
#pragma unroll
        for (int ct = 0; ct < 4; ++ct) acc[mt][ct] = (f32x4){0.f, 0.f, 0.f, 0.f};

#pragma unroll
    for (int mt = 0; mt < 3; ++mt) {
#pragma unroll
        for (int ct = 0; ct < 4; ++ct) {
#pragma unroll
            for (int ks = 0; ks < 2; ++ks) {
                const int fi = (((mt * 4 + ct) * 2 + ks) * 64 + l) * 8;
                bf16x8 bh = *(const bf16x8*)&sH[fi];
                bf16x8 bl = *(const bf16x8*)&sL[fi];
                acc[mt][ct] = __builtin_amdgcn_mfma_f32_16x16x32_bf16(
                    aH[ks], bh, acc[mt][ct], 0, 0, 0);
                acc[mt][ct] = __builtin_amdgcn_mfma_f32_16x16x32_bf16(
                    aH[ks], bl, acc[mt][ct], 0, 0, 0);
                acc[mt][ct] = __builtin_amdgcn_mfma_f32_16x16x32_bf16(
                    aL[ks], bh, acc[mt][ct], 0, 0, 0);
            }
        }
    }

    // Epilogue: lane holds original cols 4m+ct (ct=0..3), row = qd*4 + r.
#pragma unroll
    for (int r = 0; r < 4; ++r) {
        const int node = n0 + qd * 4 + r;
        if (node < N) {
            float4 oq;
            oq.x = acc[0][0][r]; oq.y = acc[0][1][r];
            oq.z = acc[0][2][r]; oq.w = acc[0][3][r];
            *(float4*)(Q + (size_t)node * 64 + 4 * m) = oq;

            uint4 kv;   // {kpack(4m,4m+1), vpack(..), kpack(4m+2,4m+3), vpack(..)}
            kv.x = (unsigned int)f32_to_bf16(acc[1][0][r]) |
                   ((unsigned int)f32_to_bf16(acc[1][1][r]) << 16);
            kv.y = (unsigned int)f32_to_bf16(acc[2][0][r]) |
                   ((unsigned int)f32_to_bf16(acc[2][1][r]) << 16);
            kv.z = (unsigned int)f32_to_bf16(acc[1][2][r]) |
                   ((unsigned int)f32_to_bf16(acc[1][3][r]) << 16);
            kv.w = (unsigned int)f32_to_bf16(acc[2][2][r]) |
                   ((unsigned int)f32_to_bf16(acc[2][3][r]) << 16);
            *(uint4*)(KVP + (size_t)node * 64 + 4 * m) = kv;   // uint2 idx 2m..2m+1
        }
    }
}

// --- Counting sort: histogram -> block sums -> scan -> binned 2-phase scatter

__global__ __launch_bounds__(256) void histo_kernel(
    const int* __restrict__ rows, int* __restrict__ cnt, int E) {
    const int e = blockIdx.x * 256 + threadIdx.x;
    if (e < E) atomicAdd(&cnt[rows[e]], 1);
}

__global__ __launch_bounds__(256) void block_sum_kernel(
    const int* __restrict__ cnt, int* __restrict__ bsum, int N) {
    __shared__ int s[256];
    const int tid = threadIdx.x;
    const int i   = blockIdx.x * 256 + tid;
    s[tid] = (i < N) ? cnt[i] : 0;
    __syncthreads();
    for (int st = 128; st > 0; st >>= 1) {
        if (tid < st) s[tid] += s[tid + st];
        __syncthreads();
    }
    if (tid == 0) bsum[blockIdx.x] = s[0];
}

// Per-chunk exclusive scan; global base computed IN-KERNEL from bsum.
// Also emits bucket append-cursors (bcur[bid] = chunk base) for scatter_bin.
__global__ __launch_bounds__(256) void block_scan_kernel(
    const int* __restrict__ cnt, const int* __restrict__ bsum,
    int* __restrict__ off, int* __restrict__ cur, int* __restrict__ bcur,
    int N, int E, int NB) {
    __shared__ int s[256];
    __shared__ int red[256];
    const int tid = threadIdx.x;
    const int bid = blockIdx.x;
    const int i   = bid * 256 + tid;

    // Global exclusive prefix of bsum for this block.
    int pacc = 0;
    for (int k = tid; k < NB; k += 256) {
        if (k < bid) pacc += bsum[k];
    }
    red[tid] = pacc;
    __syncthreads();
    for (int st = 128; st > 0; st >>= 1) {
        if (tid < st) red[tid] += red[tid + st];
        __syncthreads();
    }
    const int base = red[0];
    if (tid == 0) bcur[bid] = base;   // bucket b = nodes [b*256,(b+1)*256)

    const int x = (i < N) ? cnt[i] : 0;
    s[tid] = x;
    __syncthreads();
    for (int offs = 1; offs < 256; offs <<= 1) {
        int v = 0;
        if (tid >= offs) v = s[tid - offs];
        __syncthreads();
        if (tid >= offs) s[tid] += v;
        __syncthreads();
    }
    if (i < N) {
        const int val = base + s[tid] - x;   // exclusive
        off[i] = val;
        cur[i] = val;
    }
    if (i == 0) off[N] = E;
}

// Phase A: append packed (rel_row<<24 | col) into 256-node bucket regions.
// Appends to a bucket land in adjacent slots -> write frontier = NB hot
// lines, L2-resident -> near-full-line writebacks (vs 64B/edge before).
__global__ __launch_bounds__(256) void scatter_bin_kernel(
    const int* __restrict__ rows, const int* __restrict__ cols,
    int* __restrict__ bcur, unsigned int* __restrict__ tmp, int E) {
    const int e = blockIdx.x * 256 + threadIdx.x;
    if (e >= E) return;
    const int r = rows[e];
    const int c = cols[e];
    const int p = atomicAdd(&bcur[r >> 8], 1);
    tmp[p] = ((unsigned int)(r & 255) << 24) | (unsigned int)c;
}

// Phase B: block per bucket.  Coalesced read of bucket edges, LDS-atomic
// placement against per-node offsets, staged LDS buffer, coalesced write.
__global__ __launch_bounds__(256) void bucket_sort_kernel(
    const unsigned int* __restrict__ tmp, const int* __restrict__ off,
    int* __restrict__ cur, int* __restrict__ sc, int N) {
    __shared__ int lcur[256];
    __shared__ int sbuf[4096];
    const int b    = blockIdx.x;
    const int tid  = threadIdx.x;
    const int n0   = b * 256;
    const int nend = min(N, n0 + 256);
    const int base = off[n0];
    const int cnt_b = off[nend] - base;

    if (cnt_b <= 4096) {
        const int node = n0 + tid;
        lcur[tid] = (node < nend) ? (off[node] - base) : 0;
        __syncthreads();
        for (int i = tid; i < cnt_b; i += 256) {
            const unsigned int w = tmp[base + i];
            const int rel = (int)(w >> 24);
            const int col = (int)(w & 0x00FFFFFFu);
            const int p = atomicAdd(&lcur[rel], 1);   // LDS atomic
            sbuf[p] = col;
        }
        __syncthreads();
        for (int i = tid; i < cnt_b; i += 256) sc[base + i] = sbuf[i];
    } else {
        // Fallback (never expected at E/N=8): global-atomic placement.
        for (int i = tid; i < cnt_b; i += 256) {
            const unsigned int w = tmp[base + i];
            const int rel = (int)(w >> 24);
            const int col = (int)(w & 0x00FFFFFFu);
            const int p = atomicAdd(&cur[n0 + rel], 1);
            sc[p] = col;
        }
    }
}

// ---------------------------------------------------------------------------
// Kernel 2: atomic-free aggregation, 4 edges per wave-step.
// lane l: d = l&15 (dim quad 4d..4d+3 = one uint4 of KVP), es = l>>4 (edge
// slot).  Head reduce = 2 shfl_xor over the 4-lane group (dh=16 = 4 lanes).
// Final cross-slot combine: shfl_xor 16/32; lanes 0-15 store float4.
// ---------------------------------------------------------------------------
__device__ __forceinline__ void agg_step(const uint4 kv, const float4 q4,
                                         bool ok, float& aN, float& a0,
                                         float& a1, float& a2, float& a3) {
    float pp = q4.x * bf16lo_f32(kv.x);
    pp = fmaf(q4.y, bf16hi_f32(kv.x), pp);
    pp = fmaf(q4.z, bf16lo_f32(kv.z), pp);
    pp = fmaf(q4.w, bf16hi_f32(kv.z), pp);
    pp += __shfl_xor(pp, 1);
    pp += __shfl_xor(pp, 2);
    float e = __expf(fminf(fmaxf(pp, -10.f), 10.f));
    e = ok ? e : 0.f;
    aN += e;
    a0 = fmaf(e, bf16lo_f32(kv.y), a0);
    a1 = fmaf(e, bf16hi_f32(kv.y), a1);
    a2 = fmaf(e, bf16lo_f32(kv.w), a2);
    a3 = fmaf(e, bf16hi_f32(kv.w), a3);
}

__global__ __launch_bounds__(256) void aggregate_kernel(
    const int* __restrict__ off, const int* __restrict__ sc,
    const float* __restrict__ Q, const unsigned int* __restrict__ KVP,
    float* __restrict__ out, int N) {
    const int t = blockIdx.x * 256 + threadIdx.x;
    const int n = t >> 6;
    const int l = t & 63;
    if (n >= N) return;
    const int d  = l & 15;              // dim quad
    const int es = l >> 4;              // edge slot 0..3

    const int off0 = off[n];
    const int off1 = off[n + 1];
    const float4 q4 = *(const float4*)(Q + (size_t)n * 64 + 4 * d);

    float aN = 0.f, a0 = 0.f, a1 = 0.f, a2 = 0.f, a3 = 0.f;
    int i = off0;

    // Main: 16 edges per iteration (4 steps, 4 dwordx4 gathers in flight).
    for (; i + 15 < off1; i += 16) {
        int c[4];
        uint4 kv[4];
#pragma unroll
        for (int j = 0; j < 4; ++j) c[j] = sc[i + 4 * j + es];
#pragma unroll
        for (int j = 0; j < 4; ++j)
            kv[j] = *(const uint4*)(KVP + (size_t)c[j] * 64 + 4 * d);
#pragma unroll
        for (int j = 0; j < 4; ++j)
            agg_step(kv[j], q4, true, aN, a0, a1, a2, a3);
    }
    // 4-edge steps.
    for (; i + 3 < off1; i += 4) {
        const int c0 = sc[i + es];
        const uint4 kv0 = *(const uint4*)(KVP + (size_t)c0 * 64 + 4 * d);
        agg_step(kv0, q4, true, aN, a0, a1, a2, a3);
    }
    // Masked tail (1..3 edges).
    if (i < off1) {
        const int idx = i + es;
        const bool ok = idx < off1;
        const int c0 = sc[ok ? idx : off1 - 1];
        const uint4 kv0 = *(const uint4*)(KVP + (size_t)c0 * 64 + 4 * d);
        agg_step(kv0, q4, ok, aN, a0, a1, a2, a3);
    }

    // Combine the four edge slots.
    aN += __shfl_xor(aN, 16);  aN += __shfl_xor(aN, 32);
    a0 += __shfl_xor(a0, 16);  a0 += __shfl_xor(a0, 32);
    a1 += __shfl_xor(a1, 16);  a1 += __shfl_xor(a1, 32);
    a2 += __shfl_xor(a2, 16);  a2 += __shfl_xor(a2, 32);
    a3 += __shfl_xor(a3, 16);  a3 += __shfl_xor(a3, 32);

    if (l < 16) {
        const float inv = 1.f / (aN + 1e-8f);
        float4 o;
        o.x = a0 * inv;
        o.y = a1 * inv;
        o.z = a2 * inv;
        o.w = a3 * inv;
        *(float4*)(out + (size_t)n * 64 + 4 * d) = o;
    }
}

extern "C" void kernel_launch(void* const* d_in, const int* in_sizes, int n_in,
                              void* d_out, int out_size, void* d_ws, size_t ws_size,
                              hipStream_t stream) {
    const float* emb = (const float*)d_in[0];
    const float* Wq  = (const float*)d_in[1];
    const float* Wk  = (const float*)d_in[2];
    const float* Wv  = (const float*)d_in[3];
    const int*   w32 = (const int*)d_in[4];

    const int N  = in_sizes[0] / D;   // 100000
    const int E  = in_sizes[4] / 2;   // 800000
    const int NB = (N + 255) / 256;   // 391 (= bucket count)
    const size_t ND = (size_t)N * D;

    const int* rows = w32;            // validated r10: [2,E], rows = half 0
    const int* cols = w32 + E;

    // Workspace (~59 MB): WfH | WfL | Q f32 | KVP | cnt | off | cur | bsum |
    // bcur | sc | tmp
    unsigned short* WfH = (unsigned short*)d_ws;           // 24 KB (16B-aligned)
    unsigned short* WfL = WfH + 12288;                     // 24 KB
    float*          Q   = (float*)(WfL + 12288);           // 48 KB offset
    unsigned int*   KVP = (unsigned int*)(Q + ND);
    int*   cnt  = (int*)(KVP + ND);
    int*   off  = cnt + N;            // N+1
    int*   cur  = off + N + 1;
    int*   bsum = cur + N;
    int*   bcur = bsum + NB;
    int*   sc   = bcur + NB;
    unsigned int* tmp = (unsigned int*)(sc + E);

    float* out = (float*)d_out;

    (void)hipMemsetAsync(cnt, 0, (size_t)N * sizeof(int), stream);

    // 0) W -> hi/lo MFMA fragment order (48 KB, 48 blocks: 1 elem/thread)
    prep_w_kernel<<<48, 256, 0, stream>>>(Wq, Wk, Wv, WfH, WfL);

    // 1) QKV projection (split-precision MFMA, Wf in LDS, paired outputs)
    qkv_kernel<<<(N + 63) / 64, 256, 0, stream>>>(emb, WfH, WfL, N, Q, KVP);

    // 2) Counting sort of edges by destination (5 dispatches, binned scatter)
    histo_kernel<<<(E + 255) / 256, 256, 0, stream>>>(rows, cnt, E);
    block_sum_kernel<<<NB, 256, 0, stream>>>(cnt, bsum, N);
    block_scan_kernel<<<NB, 256, 0, stream>>>(cnt, bsum, off, cur, bcur, N, E, NB);
    scatter_bin_kernel<<<(E + 255) / 256, 256, 0, stream>>>(rows, cols, bcur, tmp, E);
    bucket_sort_kernel<<<NB, 256, 0, stream>>>(tmp, off, cur, sc, N);

    // 3) Atomic-free aggregation: one wave per node, 4 edges per wave-step
    aggregate_kernel<<<((size_t)N * 64 + 255) / 256, 256, 0, stream>>>(
        off, sc, Q, KVP, out, N);
}

// Round 3
// 208.029 us; speedup vs baseline: 2.2499x; 2.2499x over previous
//
#include <hip/hip_runtime.h>
#include <math.h>

constexpr int D = 64;
constexpr int H = 4;
constexpr int EB = 8192;   // edges per binning block

// ---------------------------------------------------------------------------
// R22: R21's binned scatter was 281us — 391 global cursors x ~2046 serial
// RMWs each = contended-atomic bound (VALUBusy 0.09%, HBM 1.6%).  Replaced
// with contention-free 2-level counting sort:
//   bin_hist:  per-block LDS histogram over 391 buckets (+ fused per-node
//              global histo, contention ~8) -> hist2d[blk][b]
//   scan2d:    per-bucket exclusive scan over blocks -> base2d[blk][b]
//              (each block owns a PRIVATE contiguous sub-range per bucket)
//   scatter2d: LDS cursors seeded from base2d; packed (rel8|col24) stores
//              land in private ~84B runs -> near-full-line writebacks
//   bucket_sort (phase B) unchanged: LDS place + coalesced sc write.
// R20: aggregate 4 edges/wave-step (lane=dim-quad d=l&15, slot es=l>>4).
// Layouts (verified learn_hip m89/m120): A[m=lane&15][k=(lane>>4)*8+j],
// B[k=(lane>>4)*8+j][n=lane&15], C/D col=lane&15 row=(lane>>4)*4+reg.
// ---------------------------------------------------------------------------

typedef __attribute__((ext_vector_type(8))) short bf16x8;
typedef __attribute__((ext_vector_type(4))) float f32x4;

__device__ __forceinline__ unsigned short f32_to_bf16(float f) {
    const unsigned int u = __float_as_uint(f);
    return (unsigned short)((u + 0x7FFFu + ((u >> 16) & 1u)) >> 16);  // RNE
}
__device__ __forceinline__ float bf16_to_f32(unsigned short h) {
    return __uint_as_float(((unsigned int)h) << 16);
}
__device__ __forceinline__ float bf16lo_f32(unsigned int w) {   // bits 0-15
    return __uint_as_float(w << 16);
}
__device__ __forceinline__ float bf16hi_f32(unsigned int w) {   // bits 16-31
    return __uint_as_float(w & 0xFFFF0000u);
}

// ---------------------------------------------------------------------------
// Kernel 0: pre-split W into hi/lo MFMA B-fragment order with PERMUTED column
// map: fragment (mt, ct, ks, lane l, j) <- W_mt[ks*32+(l>>4)*8+j][4*(l&15)+ct]
// so MFMA acc[mt][ct] at lane m holds ORIGINAL output col 4m+ct.
// ---------------------------------------------------------------------------
__global__ __launch_bounds__(256) void prep_w_kernel(
    const float* __restrict__ Wq, const float* __restrict__ Wk,
    const float* __restrict__ Wv,
    unsigned short* __restrict__ WfH, unsigned short* __restrict__ WfL) {
    const float* W[3] = {Wq, Wk, Wv};
    for (int idx = blockIdx.x * 256 + threadIdx.x; idx < 3 * 4 * 2 * 64 * 8;
         idx += gridDim.x * 256) {
        const int j  = idx & 7;
        const int l  = (idx >> 3) & 63;
        const int ks = (idx >> 9) & 1;
        const int ct = (idx >> 10) & 3;
        const int mt = idx >> 12;
        const int krow = ks * 32 + (l >> 4) * 8 + j;
        const int col  = 4 * (l & 15) + ct;          // permuted column map
        const float w  = W[mt][krow * 64 + col];
        const unsigned short h = f32_to_bf16(w);
        WfH[idx] = h;
        WfL[idx] = f32_to_bf16(w - bf16_to_f32(h));
    }
}

// ---------------------------------------------------------------------------
// Kernel 1: QKV projection via split-precision MFMA (Ah*Bh + Ah*Bl + Al*Bh).
// Block = 4 waves; wave = 16 nodes.  Wf hi/lo staged in LDS (48 KB).
// Outputs: Q fp32 (dwordx4 per lane), KVP uint2 pairs (dwordx4 per lane).
// ---------------------------------------------------------------------------
__global__ __launch_bounds__(256) void qkv_kernel(
    const float* __restrict__ emb,
    const unsigned short* __restrict__ WfH,
    const unsigned short* __restrict__ WfL,
    int N, float* __restrict__ Q, unsigned int* __restrict__ KVP) {
    __shared__ unsigned short sH[12288];   // 24 KB
    __shared__ unsigned short sL[12288];   // 24 KB
    const int tid = threadIdx.x;

    {
        const uint4* gh = (const uint4*)WfH;
        const uint4* gl = (const uint4*)WfL;
        uint4* shh = (uint4*)sH;
        uint4* sll = (uint4*)sL;
        for (int k = tid; k < 1536; k += 256) {
            shh[k] = gh[k];
            sll[k] = gl[k];
        }
    }
    __syncthreads();

    const int wv = tid >> 6;
    const int l  = tid & 63;
    const int qd = l >> 4;              // quad 0..3
    const int m  = l & 15;
    const int n0 = blockIdx.x * 64 + wv * 16;

    // A fragments, split hi/lo: k = ks*32 + qd*8 + j
    bf16x8 aH[2], aL[2];
    {
        int node = n0 + m;
        if (node >= N) node = N - 1;
        const float4* ep = (const float4*)(emb + (size_t)node * 64);
#pragma unroll
        for (int ks = 0; ks < 2; ++ks) {
            const float4 a0 = ep[ks * 8 + qd * 2 + 0];
            const float4 a1 = ep[ks * 8 + qd * 2 + 1];
            const float f[8] = {a0.x, a0.y, a0.z, a0.w, a1.x, a1.y, a1.z, a1.w};
            bf16x8 fh, fl;
#pragma unroll
            for (int j = 0; j < 8; ++j) {
                const unsigned short h = f32_to_bf16(f[j]);
                fh[j] = (short)h;
                fl[j] = (short)f32_to_bf16(f[j] - bf16_to_f32(h));
            }
            aH[ks] = fh;
            aL[ks] = fl;
        }
    }

    f32x4 acc[3][4];
#pragma unroll
    for (int mt = 0; mt < 3; ++mt)
#pragma unroll
        for (int ct = 0; ct < 4; ++ct) acc[mt][ct] = (f32x4){0.f, 0.f, 0.f, 0.f};

#pragma unroll
    for (int mt = 0; mt < 3; ++mt) {
#pragma unroll
        for (int ct = 0; ct < 4; ++ct) {
#pragma unroll
            for (int ks = 0; ks < 2; ++ks) {
                const int fi = (((mt * 4 + ct) * 2 + ks) * 64 + l) * 8;
                bf16x8 bh = *(const bf16x8*)&sH[fi];
                bf16x8 bl = *(const bf16x8*)&sL[fi];
                acc[mt][ct] = __builtin_amdgcn_mfma_f32_16x16x32_bf16(
                    aH[ks], bh, acc[mt][ct], 0, 0, 0);
                acc[mt][ct] = __builtin_amdgcn_mfma_f32_16x16x32_bf16(
                    aH[ks], bl, acc[mt][ct], 0, 0, 0);
                acc[mt][ct] = __builtin_amdgcn_mfma_f32_16x16x32_bf16(
                    aL[ks], bh, acc[mt][ct], 0, 0, 0);
            }
        }
    }

    // Epilogue: lane holds original cols 4m+ct (ct=0..3), row = qd*4 + r.
#pragma unroll
    for (int r = 0; r < 4; ++r) {
        const int node = n0 + qd * 4 + r;
        if (node < N) {
            float4 oq;
            oq.x = acc[0][0][r]; oq.y = acc[0][1][r];
            oq.z = acc[0][2][r]; oq.w = acc[0][3][r];
            *(float4*)(Q + (size_t)node * 64 + 4 * m) = oq;

            uint4 kv;   // {kpack(4m,4m+1), vpack(..), kpack(4m+2,4m+3), vpack(..)}
            kv.x = (unsigned int)f32_to_bf16(acc[1][0][r]) |
                   ((unsigned int)f32_to_bf16(acc[1][1][r]) << 16);
            kv.y = (unsigned int)f32_to_bf16(acc[2][0][r]) |
                   ((unsigned int)f32_to_bf16(acc[2][1][r]) << 16);
            kv.z = (unsigned int)f32_to_bf16(acc[1][2][r]) |
                   ((unsigned int)f32_to_bf16(acc[1][3][r]) << 16);
            kv.w = (unsigned int)f32_to_bf16(acc[2][2][r]) |
                   ((unsigned int)f32_to_bf16(acc[2][3][r]) << 16);
            *(uint4*)(KVP + (size_t)node * 64 + 4 * m) = kv;   // uint2 idx 2m..2m+1
        }
    }
}

// --- Counting sort: fused histo+2D-bin hist -> scans -> private scatter ----

// Per-block LDS histogram over 256-node buckets + fused per-node global histo.
__global__ __launch_bounds__(256) void bin_hist_kernel(
    const int* __restrict__ rows, int* __restrict__ cnt,
    int* __restrict__ hist2d, int E, int NB) {
    __shared__ int h[512];
    const int tid = threadIdx.x;
    const int blk = blockIdx.x;
    for (int b = tid; b < NB; b += 256) h[b] = 0;
    __syncthreads();
    const int e0 = blk * EB;
    const int e1 = min(E, e0 + EB);
    for (int i = e0 + tid; i < e1; i += 256) {
        const int r = rows[i];
        atomicAdd(&cnt[r], 1);        // global, avg contention E/N = 8
        atomicAdd(&h[r >> 8], 1);     // LDS, avg contention EB/NB ~ 21
    }
    __syncthreads();
    for (int b = tid; b < NB; b += 256) hist2d[blk * NB + b] = h[b];
}

__global__ __launch_bounds__(256) void block_sum_kernel(
    const int* __restrict__ cnt, int* __restrict__ bsum, int N) {
    __shared__ int s[256];
    const int tid = threadIdx.x;
    const int i   = blockIdx.x * 256 + tid;
    s[tid] = (i < N) ? cnt[i] : 0;
    __syncthreads();
    for (int st = 128; st > 0; st >>= 1) {
        if (tid < st) s[tid] += s[tid + st];
        __syncthreads();
    }
    if (tid == 0) bsum[blockIdx.x] = s[0];
}

// Per-chunk exclusive scan; global base computed IN-KERNEL from bsum.
__global__ __launch_bounds__(256) void block_scan_kernel(
    const int* __restrict__ cnt, const int* __restrict__ bsum,
    int* __restrict__ off, int* __restrict__ cur, int N, int E, int NB) {
    __shared__ int s[256];
    __shared__ int red[256];
    const int tid = threadIdx.x;
    const int bid = blockIdx.x;
    const int i   = bid * 256 + tid;

    // Global exclusive prefix of bsum for this block.
    int pacc = 0;
    for (int k = tid; k < NB; k += 256) {
        if (k < bid) pacc += bsum[k];
    }
    red[tid] = pacc;
    __syncthreads();
    for (int st = 128; st > 0; st >>= 1) {
        if (tid < st) red[tid] += red[tid + st];
        __syncthreads();
    }
    const int base = red[0];

    const int x = (i < N) ? cnt[i] : 0;
    s[tid] = x;
    __syncthreads();
    for (int offs = 1; offs < 256; offs <<= 1) {
        int v = 0;
        if (tid >= offs) v = s[tid - offs];
        __syncthreads();
        if (tid >= offs) s[tid] += v;
        __syncthreads();
    }
    if (i < N) {
        const int val = base + s[tid] - x;   // exclusive
        off[i] = val;
        cur[i] = val;
    }
    if (i == 0) off[N] = E;
}

// Per-bucket exclusive scan over binning blocks: base2d[blk][b] =
// off[b*256] + sum_{blk'<blk} hist2d[blk'][b].  One block per bucket.
__global__ __launch_bounds__(256) void scan2d_kernel(
    const int* __restrict__ hist2d, const int* __restrict__ off,
    int* __restrict__ base2d, int NBLK, int NB) {
    __shared__ int s[256];
    const int b   = blockIdx.x;
    const int tid = threadIdx.x;
    const int x = (tid < NBLK) ? hist2d[tid * NB + b] : 0;
    s[tid] = x;
    __syncthreads();
    for (int o = 1; o < 256; o <<= 1) {
        int v = 0;
        if (tid >= o) v = s[tid - o];
        __syncthreads();
        if (tid >= o) s[tid] += v;
        __syncthreads();
    }
    if (tid < NBLK) base2d[tid * NB + b] = off[b * 256] + s[tid] - x;
}

// Phase A: each block places its edges into PRIVATE per-bucket sub-ranges
// via LDS cursors -> zero global atomics, ~84B contiguous write runs.
__global__ __launch_bounds__(256) void scatter2d_kernel(
    const int* __restrict__ rows, const int* __restrict__ cols,
    const int* __restrict__ base2d, unsigned int* __restrict__ tmp,
    int E, int NB) {
    __shared__ int lcur[512];
    const int tid = threadIdx.x;
    const int blk = blockIdx.x;
    for (int b = tid; b < NB; b += 256) lcur[b] = base2d[blk * NB + b];
    __syncthreads();
    const int e0 = blk * EB;
    const int e1 = min(E, e0 + EB);
    for (int i = e0 + tid; i < e1; i += 256) {
        const int r = rows[i];
        const int c = cols[i];
        const int p = atomicAdd(&lcur[r >> 8], 1);   // LDS atomic
        tmp[p] = ((unsigned int)(r & 255) << 24) | (unsigned int)c;
    }
}

// Phase B: block per bucket.  Coalesced read of bucket edges, LDS-atomic
// placement against per-node offsets, staged LDS buffer, coalesced write.
__global__ __launch_bounds__(256) void bucket_sort_kernel(
    const unsigned int* __restrict__ tmp, const int* __restrict__ off,
    int* __restrict__ cur, int* __restrict__ sc, int N) {
    __shared__ int lcur[256];
    __shared__ int sbuf[4096];
    const int b    = blockIdx.x;
    const int tid  = threadIdx.x;
    const int n0   = b * 256;
    const int nend = min(N, n0 + 256);
    const int base = off[n0];
    const int cnt_b = off[nend] - base;

    if (cnt_b <= 4096) {
        const int node = n0 + tid;
        lcur[tid] = (node < nend) ? (off[node] - base) : 0;
        __syncthreads();
        for (int i = tid; i < cnt_b; i += 256) {
            const unsigned int w = tmp[base + i];
            const int rel = (int)(w >> 24);
            const int col = (int)(w & 0x00FFFFFFu);
            const int p = atomicAdd(&lcur[rel], 1);   // LDS atomic
            sbuf[p] = col;
        }
        __syncthreads();
        for (int i = tid; i < cnt_b; i += 256) sc[base + i] = sbuf[i];
    } else {
        // Fallback (never expected at E/N=8): global-atomic placement.
        for (int i = tid; i < cnt_b; i += 256) {
            const unsigned int w = tmp[base + i];
            const int rel = (int)(w >> 24);
            const int col = (int)(w & 0x00FFFFFFu);
            const int p = atomicAdd(&cur[n0 + rel], 1);
            sc[p] = col;
        }
    }
}

// ---------------------------------------------------------------------------
// Kernel 2: atomic-free aggregation, 4 edges per wave-step.
// lane l: d = l&15 (dim quad 4d..4d+3 = one uint4 of KVP), es = l>>4 (edge
// slot).  Head reduce = 2 shfl_xor over the 4-lane group (dh=16 = 4 lanes).
// Final cross-slot combine: shfl_xor 16/32; lanes 0-15 store float4.
// ---------------------------------------------------------------------------
__device__ __forceinline__ void agg_step(const uint4 kv, const float4 q4,
                                         bool ok, float& aN, float& a0,
                                         float& a1, float& a2, float& a3) {
    float pp = q4.x * bf16lo_f32(kv.x);
    pp = fmaf(q4.y, bf16hi_f32(kv.x), pp);
    pp = fmaf(q4.z, bf16lo_f32(kv.z), pp);
    pp = fmaf(q4.w, bf16hi_f32(kv.z), pp);
    pp += __shfl_xor(pp, 1);
    pp += __shfl_xor(pp, 2);
    float e = __expf(fminf(fmaxf(pp, -10.f), 10.f));
    e = ok ? e : 0.f;
    aN += e;
    a0 = fmaf(e, bf16lo_f32(kv.y), a0);
    a1 = fmaf(e, bf16hi_f32(kv.y), a1);
    a2 = fmaf(e, bf16lo_f32(kv.w), a2);
    a3 = fmaf(e, bf16hi_f32(kv.w), a3);
}

__global__ __launch_bounds__(256) void aggregate_kernel(
    const int* __restrict__ off, const int* __restrict__ sc,
    const float* __restrict__ Q, const unsigned int* __restrict__ KVP,
    float* __restrict__ out, int N) {
    const int t = blockIdx.x * 256 + threadIdx.x;
    const int n = t >> 6;
    const int l = t & 63;
    if (n >= N) return;
    const int d  = l & 15;              // dim quad
    const int es = l >> 4;              // edge slot 0..3

    const int off0 = off[n];
    const int off1 = off[n + 1];
    const float4 q4 = *(const float4*)(Q + (size_t)n * 64 + 4 * d);

    float aN = 0.f, a0 = 0.f, a1 = 0.f, a2 = 0.f, a3 = 0.f;
    int i = off0;

    // Main: 16 edges per iteration (4 steps, 4 dwordx4 gathers in flight).
    for (; i + 15 < off1; i += 16) {
        int c[4];
        uint4 kv[4];
#pragma unroll
        for (int j = 0; j < 4; ++j) c[j] = sc[i + 4 * j + es];
#pragma unroll
        for (int j = 0; j < 4; ++j)
            kv[j] = *(const uint4*)(KVP + (size_t)c[j] * 64 + 4 * d);
#pragma unroll
        for (int j = 0; j < 4; ++j)
            agg_step(kv[j], q4, true, aN, a0, a1, a2, a3);
    }
    // 4-edge steps.
    for (; i + 3 < off1; i += 4) {
        const int c0 = sc[i + es];
        const uint4 kv0 = *(const uint4*)(KVP + (size_t)c0 * 64 + 4 * d);
        agg_step(kv0, q4, true, aN, a0, a1, a2, a3);
    }
    // Masked tail (1..3 edges).
    if (i < off1) {
        const int idx = i + es;
        const bool ok = idx < off1;
        const int c0 = sc[ok ? idx : off1 - 1];
        const uint4 kv0 = *(const uint4*)(KVP + (size_t)c0 * 64 + 4 * d);
        agg_step(kv0, q4, ok, aN, a0, a1, a2, a3);
    }

    // Combine the four edge slots.
    aN += __shfl_xor(aN, 16);  aN += __shfl_xor(aN, 32);
    a0 += __shfl_xor(a0, 16);  a0 += __shfl_xor(a0, 32);
    a1 += __shfl_xor(a1, 16);  a1 += __shfl_xor(a1, 32);
    a2 += __shfl_xor(a2, 16);  a2 += __shfl_xor(a2, 32);
    a3 += __shfl_xor(a3, 16);  a3 += __shfl_xor(a3, 32);

    if (l < 16) {
        const float inv = 1.f / (aN + 1e-8f);
        float4 o;
        o.x = a0 * inv;
        o.y = a1 * inv;
        o.z = a2 * inv;
        o.w = a3 * inv;
        *(float4*)(out + (size_t)n * 64 + 4 * d) = o;
    }
}

extern "C" void kernel_launch(void* const* d_in, const int* in_sizes, int n_in,
                              void* d_out, int out_size, void* d_ws, size_t ws_size,
                              hipStream_t stream) {
    const float* emb = (const float*)d_in[0];
    const float* Wq  = (const float*)d_in[1];
    const float* Wk  = (const float*)d_in[2];
    const float* Wv  = (const float*)d_in[3];
    const int*   w32 = (const int*)d_in[4];

    const int N    = in_sizes[0] / D;   // 100000
    const int E    = in_sizes[4] / 2;   // 800000
    const int NB   = (N + 255) / 256;   // 391 (= bucket count)
    const int NBLK = (E + EB - 1) / EB; // 98 binning blocks
    const size_t ND = (size_t)N * D;

    const int* rows = w32;            // validated r10: [2,E], rows = half 0
    const int* cols = w32 + E;

    // Workspace (~59 MB): WfH | WfL | Q f32 | KVP | cnt | off | cur | bsum |
    // sc | tmp | hist2d | base2d
    unsigned short* WfH = (unsigned short*)d_ws;           // 24 KB (16B-aligned)
    unsigned short* WfL = WfH + 12288;                     // 24 KB
    float*          Q   = (float*)(WfL + 12288);           // 48 KB offset
    unsigned int*   KVP = (unsigned int*)(Q + ND);
    int*   cnt  = (int*)(KVP + ND);
    int*   off  = cnt + N;            // N+1
    int*   cur  = off + N + 1;
    int*   bsum = cur + N;
    int*   sc   = bsum + NB + (NB & 1);
    unsigned int* tmp = (unsigned int*)(sc + E);
    int*   hist2d = (int*)(tmp + E);  // NBLK*NB ints (~153 KB)
    int*   base2d = hist2d + NBLK * NB;

    float* out = (float*)d_out;

    (void)hipMemsetAsync(cnt, 0, (size_t)N * sizeof(int), stream);

    // 0) W -> hi/lo MFMA fragment order (48 KB, 48 blocks: 1 elem/thread)
    prep_w_kernel<<<48, 256, 0, stream>>>(Wq, Wk, Wv, WfH, WfL);

    // 1) QKV projection (split-precision MFMA, Wf in LDS, paired outputs)
    qkv_kernel<<<(N + 63) / 64, 256, 0, stream>>>(emb, WfH, WfL, N, Q, KVP);

    // 2) Counting sort of edges by destination (6 small dispatches)
    bin_hist_kernel<<<NBLK, 256, 0, stream>>>(rows, cnt, hist2d, E, NB);
    block_sum_kernel<<<NB, 256, 0, stream>>>(cnt, bsum, N);
    block_scan_kernel<<<NB, 256, 0, stream>>>(cnt, bsum, off, cur, N, E, NB);
    scan2d_kernel<<<NB, 256, 0, stream>>>(hist2d, off, base2d, NBLK, NB);
    scatter2d_kernel<<<NBLK, 256, 0, stream>>>(rows, cols, base2d, tmp, E, NB);
    bucket_sort_kernel<<<NB, 256, 0, stream>>>(tmp, off, cur, sc, N);

    // 3) Atomic-free aggregation: one wave per node, 4 edges per wave-step
    aggregate_kernel<<<((size_t)N * 64 + 255) / 256, 256, 0, stream>>>(
        off, sc, Q, KVP, out, N);
}

// Round 4
// 166.248 us; speedup vs baseline: 2.8153x; 1.2513x over previous
//
#include <hip/hip_runtime.h>
#include <math.h>

constexpr int D = 64;
constexpr int H = 4;
constexpr int EB = 8192;   // edges per binning block

// ---------------------------------------------------------------------------
// R23: two attacks on the latency-bound remainder.
// (1) aggregate: one coalesced wave-load of up to 64 edge indices
//     (myc=sc[off0+l]); per-16-edge group the 4 step indices come from
//     __shfl (register) instead of dependent sc loads -> all 4 gathers
//     issue back-to-back even at deg~8 (masked steps clamp to last valid
//     edge; their gathers are L1 dup hits).  Serial chain/node ~1400->850cy.
// (2) sort pipeline consolidated 10->6 dispatches: per-node offsets now
//     computed INSIDE bucket_sort (LDS hist + scan of the bucket's edges),
//     killing cnt/cur/memset/histo-atomics/block_sum/block_scan; bin_hist
//     fused into the qkv dispatch (independent, fills machine together);
//     tiny bscan (1 blk) scans 391 bucket totals.
// R22: contention-free 2-level counting sort (hist2d/base2d, private
// per-(block,bucket) sub-ranges).  R20: aggregate lane=dim-quad d=l&15,
// edge slot es=l>>4, 4 edges/wave-step.
// Layouts (verified learn_hip m89/m120): A[m=lane&15][k=(lane>>4)*8+j],
// B[k=(lane>>4)*8+j][n=lane&15], C/D col=lane&15 row=(lane>>4)*4+reg.
// ---------------------------------------------------------------------------

typedef __attribute__((ext_vector_type(8))) short bf16x8;
typedef __attribute__((ext_vector_type(4))) float f32x4;

__device__ __forceinline__ unsigned short f32_to_bf16(float f) {
    const unsigned int u = __float_as_uint(f);
    return (unsigned short)((u + 0x7FFFu + ((u >> 16) & 1u)) >> 16);  // RNE
}
__device__ __forceinline__ float bf16_to_f32(unsigned short h) {
    return __uint_as_float(((unsigned int)h) << 16);
}
__device__ __forceinline__ float bf16lo_f32(unsigned int w) {   // bits 0-15
    return __uint_as_float(w << 16);
}
__device__ __forceinline__ float bf16hi_f32(unsigned int w) {   // bits 16-31
    return __uint_as_float(w & 0xFFFF0000u);
}

// ---------------------------------------------------------------------------
// Kernel 0: pre-split W into hi/lo MFMA B-fragment order with PERMUTED column
// map: fragment (mt, ct, ks, lane l, j) <- W_mt[ks*32+(l>>4)*8+j][4*(l&15)+ct]
// so MFMA acc[mt][ct] at lane m holds ORIGINAL output col 4m+ct.
// ---------------------------------------------------------------------------
__global__ __launch_bounds__(256) void prep_w_kernel(
    const float* __restrict__ Wq, const float* __restrict__ Wk,
    const float* __restrict__ Wv,
    unsigned short* __restrict__ WfH, unsigned short* __restrict__ WfL) {
    const float* W[3] = {Wq, Wk, Wv};
    for (int idx = blockIdx.x * 256 + threadIdx.x; idx < 3 * 4 * 2 * 64 * 8;
         idx += gridDim.x * 256) {
        const int j  = idx & 7;
        const int l  = (idx >> 3) & 63;
        const int ks = (idx >> 9) & 1;
        const int ct = (idx >> 10) & 3;
        const int mt = idx >> 12;
        const int krow = ks * 32 + (l >> 4) * 8 + j;
        const int col  = 4 * (l & 15) + ct;          // permuted column map
        const float w  = W[mt][krow * 64 + col];
        const unsigned short h = f32_to_bf16(w);
        WfH[idx] = h;
        WfL[idx] = f32_to_bf16(w - bf16_to_f32(h));
    }
}

// ---------------------------------------------------------------------------
// Kernel 1 (fused): blocks [0,HB) = bin_hist (LDS-only bucket histogram,
// no global atomics); blocks [HB,HB+QB) = QKV projection via split-precision
// MFMA.  Independent work, one dispatch fills the machine.
// ---------------------------------------------------------------------------
__global__ __launch_bounds__(256) void fused_qkv_hist_kernel(
    const float* __restrict__ emb,
    const unsigned short* __restrict__ WfH,
    const unsigned short* __restrict__ WfL,
    int N, float* __restrict__ Q, unsigned int* __restrict__ KVP,
    const int* __restrict__ rows, int* __restrict__ hist2d,
    int E, int NB, int HB) {
    __shared__ unsigned short sH[12288];   // 24 KB
    __shared__ unsigned short sL[12288];   // 24 KB
    __shared__ int h[512];                 // 2 KB (bin_hist part)
    const int tid = threadIdx.x;

    if ((int)blockIdx.x < HB) {
        // ---- bin_hist: per-block LDS histogram over 256-node buckets ----
        const int blk = blockIdx.x;
        for (int b = tid; b < NB; b += 256) h[b] = 0;
        __syncthreads();
        const int e0 = blk * EB;
        const int e1 = min(E, e0 + EB);
        for (int i = e0 + tid; i < e1; i += 256)
            atomicAdd(&h[rows[i] >> 8], 1);            // LDS, contention ~21
        __syncthreads();
        for (int b = tid; b < NB; b += 256) hist2d[blk * NB + b] = h[b];
        return;
    }

    // ---- qkv ----
    const int bx = blockIdx.x - HB;
    {
        const uint4* gh = (const uint4*)WfH;
        const uint4* gl = (const uint4*)WfL;
        uint4* shh = (uint4*)sH;
        uint4* sll = (uint4*)sL;
        for (int k = tid; k < 1536; k += 256) {
            shh[k] = gh[k];
            sll[k] = gl[k];
        }
    }
    __syncthreads();

    const int wv = tid >> 6;
    const int l  = tid & 63;
    const int qd = l >> 4;              // quad 0..3
    const int m  = l & 15;
    const int n0 = bx * 64 + wv * 16;

    // A fragments, split hi/lo: k = ks*32 + qd*8 + j
    bf16x8 aH[2], aL[2];
    {
        int node = n0 + m;
        if (node >= N) node = N - 1;
        const float4* ep = (const float4*)(emb + (size_t)node * 64);
#pragma unroll
        for (int ks = 0; ks < 2; ++ks) {
            const float4 a0 = ep[ks * 8 + qd * 2 + 0];
            const float4 a1 = ep[ks * 8 + qd * 2 + 1];
            const float f[8] = {a0.x, a0.y, a0.z, a0.w, a1.x, a1.y, a1.z, a1.w};
            bf16x8 fh, fl;
#pragma unroll
            for (int j = 0; j < 8; ++j) {
                const unsigned short hh = f32_to_bf16(f[j]);
                fh[j] = (short)hh;
                fl[j] = (short)f32_to_bf16(f[j] - bf16_to_f32(hh));
            }
            aH[ks] = fh;
            aL[ks] = fl;
        }
    }

    f32x4 acc[3][4];
#pragma unroll
    for (int mt = 0; mt < 3; ++mt)
#pragma unroll
        for (int ct = 0; ct < 4; ++ct) acc[mt][ct] = (f32x4){0.f, 0.f, 0.f, 0.f};

#pragma unroll
    for (int mt = 0; mt < 3; ++mt) {
#pragma unroll
        for (int ct = 0; ct < 4; ++ct) {
#pragma unroll
            for (int ks = 0; ks < 2; ++ks) {
                const int fi = (((mt * 4 + ct) * 2 + ks) * 64 + l) * 8;
                bf16x8 bh = *(const bf16x8*)&sH[fi];
                bf16x8 bl = *(const bf16x8*)&sL[fi];
                acc[mt][ct] = __builtin_amdgcn_mfma_f32_16x16x32_bf16(
                    aH[ks], bh, acc[mt][ct], 0, 0, 0);
                acc[mt][ct] = __builtin_amdgcn_mfma_f32_16x16x32_bf16(
                    aH[ks], bl, acc[mt][ct], 0, 0, 0);
                acc[mt][ct] = __builtin_amdgcn_mfma_f32_16x16x32_bf16(
                    aL[ks], bh, acc[mt][ct], 0, 0, 0);
            }
        }
    }

    // Epilogue: lane holds original cols 4m+ct (ct=0..3), row = qd*4 + r.
#pragma unroll
    for (int r = 0; r < 4; ++r) {
        const int node = n0 + qd * 4 + r;
        if (node < N) {
            float4 oq;
            oq.x = acc[0][0][r]; oq.y = acc[0][1][r];
            oq.z = acc[0][2][r]; oq.w = acc[0][3][r];
            *(float4*)(Q + (size_t)node * 64 + 4 * m) = oq;

            uint4 kv;   // {kpack(4m,4m+1), vpack(..), kpack(4m+2,4m+3), vpack(..)}
            kv.x = (unsigned int)f32_to_bf16(acc[1][0][r]) |
                   ((unsigned int)f32_to_bf16(acc[1][1][r]) << 16);
            kv.y = (unsigned int)f32_to_bf16(acc[2][0][r]) |
                   ((unsigned int)f32_to_bf16(acc[2][1][r]) << 16);
            kv.z = (unsigned int)f32_to_bf16(acc[1][2][r]) |
                   ((unsigned int)f32_to_bf16(acc[1][3][r]) << 16);
            kv.w = (unsigned int)f32_to_bf16(acc[2][2][r]) |
                   ((unsigned int)f32_to_bf16(acc[2][3][r]) << 16);
            *(uint4*)(KVP + (size_t)node * 64 + 4 * m) = kv;
        }
    }
}

// Per-bucket exclusive scan over binning blocks (column b of hist2d).
// base2d[blk][b] = prefix within bucket (WITHOUT bucket base); btot[b]=total.
__global__ __launch_bounds__(256) void scan2d_kernel(
    const int* __restrict__ hist2d, int* __restrict__ base2d,
    int* __restrict__ btot, int NBLK, int NB) {
    __shared__ int s[256];
    const int b   = blockIdx.x;
    const int tid = threadIdx.x;
    const int x = (tid < NBLK) ? hist2d[tid * NB + b] : 0;
    s[tid] = x;
    __syncthreads();
    for (int o = 1; o < 256; o <<= 1) {
        int v = 0;
        if (tid >= o) v = s[tid - o];
        __syncthreads();
        if (tid >= o) s[tid] += v;
        __syncthreads();
    }
    if (tid < NBLK) base2d[tid * NB + b] = s[tid] - x;
    if (tid == 255) btot[b] = s[255];
}

// Exclusive scan of the NB bucket totals (1 block, chunked).
__global__ __launch_bounds__(256) void bscan_kernel(
    const int* __restrict__ btot, int* __restrict__ bbase, int NB) {
    __shared__ int s[256];
    __shared__ int carry;
    const int tid = threadIdx.x;
    if (tid == 0) carry = 0;
    __syncthreads();
    for (int base = 0; base < NB; base += 256) {
        const int i = base + tid;
        const int x = (i < NB) ? btot[i] : 0;
        s[tid] = x;
        __syncthreads();
        for (int o = 1; o < 256; o <<= 1) {
            int v = 0;
            if (tid >= o) v = s[tid - o];
            __syncthreads();
            if (tid >= o) s[tid] += v;
            __syncthreads();
        }
        if (i < NB) bbase[i] = carry + s[tid] - x;
        __syncthreads();
        if (tid == 255) carry += s[255];
        __syncthreads();
    }
}

// Phase A: each block places its edges into PRIVATE per-bucket sub-ranges
// via LDS cursors -> zero global atomics, contiguous write runs.
__global__ __launch_bounds__(256) void scatter2d_kernel(
    const int* __restrict__ rows, const int* __restrict__ cols,
    const int* __restrict__ base2d, const int* __restrict__ bbase,
    unsigned int* __restrict__ tmp, int E, int NB) {
    __shared__ int lcur[512];
    const int tid = threadIdx.x;
    const int blk = blockIdx.x;
    for (int b = tid; b < NB; b += 256)
        lcur[b] = bbase[b] + base2d[blk * NB + b];
    __syncthreads();
    const int e0 = blk * EB;
    const int e1 = min(E, e0 + EB);
    for (int i = e0 + tid; i < e1; i += 256) {
        const int r = rows[i];
        const int c = cols[i];
        const int p = atomicAdd(&lcur[r >> 8], 1);   // LDS atomic
        tmp[p] = ((unsigned int)(r & 255) << 24) | (unsigned int)c;
    }
}

// Phase B: block per bucket.  Self-contained: LDS histogram of the bucket's
// edges -> per-node offsets (writes off[]) -> LDS placement -> coalesced sc.
__global__ __launch_bounds__(256) void bucket_sort_kernel(
    const unsigned int* __restrict__ tmp, const int* __restrict__ bbase,
    const int* __restrict__ btot, int* __restrict__ off,
    int* __restrict__ sc, int N, int E, int NB) {
    __shared__ unsigned int ebuf[4096];   // 16 KB
    __shared__ int sbuf[4096];            // 16 KB
    __shared__ int lhist[256];
    __shared__ int s[256];
    __shared__ int lcur[256];
    const int b     = blockIdx.x;
    const int tid   = threadIdx.x;
    const int n0    = b * 256;
    const int gbase = bbase[b];
    const int cnt_b = btot[b];

    lhist[tid] = 0;
    __syncthreads();

    if (cnt_b <= 4096) {
        for (int i = tid; i < cnt_b; i += 256) {
            const unsigned int w = tmp[gbase + i];
            ebuf[i] = w;
            atomicAdd(&lhist[w >> 24], 1);            // LDS, contention ~8
        }
        __syncthreads();
        // exclusive scan of lhist
        const int x = lhist[tid];
        s[tid] = x;
        __syncthreads();
        for (int o = 1; o < 256; o <<= 1) {
            int v = 0;
            if (tid >= o) v = s[tid - o];
            __syncthreads();
            if (tid >= o) s[tid] += v;
            __syncthreads();
        }
        const int excl = s[tid] - x;
        const int node = n0 + tid;
        if (node < N) off[node] = gbase + excl;
        if (b == NB - 1 && tid == 0) off[N] = E;
        lcur[tid] = excl;
        __syncthreads();
        for (int i = tid; i < cnt_b; i += 256) {
            const unsigned int w = ebuf[i];
            const int p = atomicAdd(&lcur[w >> 24], 1);
            sbuf[p] = (int)(w & 0x00FFFFFFu);
        }
        __syncthreads();
        for (int i = tid; i < cnt_b; i += 256) sc[gbase + i] = sbuf[i];
    } else {
        // Fallback (never expected at E/N=8): direct global placement.
        for (int i = tid; i < cnt_b; i += 256)
            atomicAdd(&lhist[tmp[gbase + i] >> 24], 1);
        __syncthreads();
        const int x = lhist[tid];
        s[tid] = x;
        __syncthreads();
        for (int o = 1; o < 256; o <<= 1) {
            int v = 0;
            if (tid >= o) v = s[tid - o];
            __syncthreads();
            if (tid >= o) s[tid] += v;
            __syncthreads();
        }
        const int excl = s[tid] - x;
        const int node = n0 + tid;
        if (node < N) off[node] = gbase + excl;
        if (b == NB - 1 && tid == 0) off[N] = E;
        lcur[tid] = excl;
        __syncthreads();
        for (int i = tid; i < cnt_b; i += 256) {
            const unsigned int w = tmp[gbase + i];
            const int p = atomicAdd(&lcur[w >> 24], 1);
            sc[gbase + p] = (int)(w & 0x00FFFFFFu);
        }
    }
}

// ---------------------------------------------------------------------------
// Kernel 2: atomic-free aggregation.  lane l: d=l&15 (dim quad, one uint4 of
// KVP), es=l>>4 (edge slot).  NEW: one coalesced wave-load of <=64 edge
// indices; per-16-edge group, step indices via __shfl -> 4 independent
// gathers in flight even at deg~8.  Masked steps clamp to last valid edge
// (dup gather = L1 hit; contribution zeroed).
// ---------------------------------------------------------------------------
__device__ __forceinline__ void agg_step(const uint4 kv, const float4 q4,
                                         bool ok, float& aN, float& a0,
                                         float& a1, float& a2, float& a3) {
    float pp = q4.x * bf16lo_f32(kv.x);
    pp = fmaf(q4.y, bf16hi_f32(kv.x), pp);
    pp = fmaf(q4.z, bf16lo_f32(kv.z), pp);
    pp = fmaf(q4.w, bf16hi_f32(kv.z), pp);
    pp += __shfl_xor(pp, 1);
    pp += __shfl_xor(pp, 2);
    float e = __expf(fminf(fmaxf(pp, -10.f), 10.f));
    e = ok ? e : 0.f;
    aN += e;
    a0 = fmaf(e, bf16lo_f32(kv.y), a0);
    a1 = fmaf(e, bf16hi_f32(kv.y), a1);
    a2 = fmaf(e, bf16lo_f32(kv.w), a2);
    a3 = fmaf(e, bf16hi_f32(kv.w), a3);
}

__global__ __launch_bounds__(256) void aggregate_kernel(
    const int* __restrict__ off, const int* __restrict__ sc,
    const float* __restrict__ Q, const unsigned int* __restrict__ KVP,
    float* __restrict__ out, int N) {
    const int t = blockIdx.x * 256 + threadIdx.x;
    const int n = t >> 6;
    const int l = t & 63;
    if (n >= N) return;
    const int d  = l & 15;              // dim quad
    const int es = l >> 4;              // edge slot 0..3

    const int off0 = off[n];
    const int off1 = off[n + 1];
    const int deg  = off1 - off0;
    const float4 q4 = *(const float4*)(Q + (size_t)n * 64 + 4 * d);

    float aN = 0.f, a0 = 0.f, a1 = 0.f, a2 = 0.f, a3 = 0.f;

    for (int base = 0; base < deg; base += 64) {
        const int cnt = min(64, deg - base);
        int myc = 0;
        if (l < cnt) myc = sc[off0 + base + l];   // coalesced, 1 wave-load
        const int ngr = (cnt + 15) >> 4;
        for (int g = 0; g < ngr; ++g) {
            int eidx[4];
            bool okv[4];
            int cc[4];
            uint4 kv[4];
#pragma unroll
            for (int si = 0; si < 4; ++si) {
                const int ei = g * 16 + 4 * si + es;
                okv[si]  = ei < cnt;
                eidx[si] = okv[si] ? ei : (cnt - 1);
            }
#pragma unroll
            for (int si = 0; si < 4; ++si) cc[si] = __shfl(myc, eidx[si]);
#pragma unroll
            for (int si = 0; si < 4; ++si)
                kv[si] = *(const uint4*)(KVP + (size_t)cc[si] * 64 + 4 * d);
#pragma unroll
            for (int si = 0; si < 4; ++si)
                agg_step(kv[si], q4, okv[si], aN, a0, a1, a2, a3);
        }
    }

    // Combine the four edge slots.
    aN += __shfl_xor(aN, 16);  aN += __shfl_xor(aN, 32);
    a0 += __shfl_xor(a0, 16);  a0 += __shfl_xor(a0, 32);
    a1 += __shfl_xor(a1, 16);  a1 += __shfl_xor(a1, 32);
    a2 += __shfl_xor(a2, 16);  a2 += __shfl_xor(a2, 32);
    a3 += __shfl_xor(a3, 16);  a3 += __shfl_xor(a3, 32);

    if (l < 16) {
        const float inv = 1.f / (aN + 1e-8f);
        float4 o;
        o.x = a0 * inv;
        o.y = a1 * inv;
        o.z = a2 * inv;
        o.w = a3 * inv;
        *(float4*)(out + (size_t)n * 64 + 4 * d) = o;
    }
}

extern "C" void kernel_launch(void* const* d_in, const int* in_sizes, int n_in,
                              void* d_out, int out_size, void* d_ws, size_t ws_size,
                              hipStream_t stream) {
    const float* emb = (const float*)d_in[0];
    const float* Wq  = (const float*)d_in[1];
    const float* Wk  = (const float*)d_in[2];
    const float* Wv  = (const float*)d_in[3];
    const int*   w32 = (const int*)d_in[4];

    const int N    = in_sizes[0] / D;   // 100000
    const int E    = in_sizes[4] / 2;   // 800000
    const int NB   = (N + 255) / 256;   // 391 buckets
    const int NBLK = (E + EB - 1) / EB; // 98 binning blocks
    const int QB   = (N + 63) / 64;     // 1563 qkv blocks
    const size_t ND = (size_t)N * D;

    const int* rows = w32;            // validated r10: [2,E], rows = half 0
    const int* cols = w32 + E;

    // Workspace: WfH | WfL | Q f32 | KVP | off | sc | tmp | hist2d | base2d |
    // btot | bbase   (~58 MB)
    unsigned short* WfH = (unsigned short*)d_ws;           // 24 KB
    unsigned short* WfL = WfH + 12288;                     // 24 KB
    float*          Q   = (float*)(WfL + 12288);
    unsigned int*   KVP = (unsigned int*)(Q + ND);
    int*   off  = (int*)(KVP + ND);   // N+1
    int*   sc   = off + N + 2;
    unsigned int* tmp = (unsigned int*)(sc + E);
    int*   hist2d = (int*)(tmp + E);  // NBLK*NB
    int*   base2d = hist2d + NBLK * NB;
    int*   btot   = base2d + NBLK * NB;
    int*   bbase  = btot + NB;

    float* out = (float*)d_out;

    // 0) W -> hi/lo MFMA fragment order
    prep_w_kernel<<<48, 256, 0, stream>>>(Wq, Wk, Wv, WfH, WfL);

    // 1) fused: bin_hist (blocks [0,NBLK)) + QKV (blocks [NBLK,NBLK+QB))
    fused_qkv_hist_kernel<<<NBLK + QB, 256, 0, stream>>>(
        emb, WfH, WfL, N, Q, KVP, rows, hist2d, E, NB, NBLK);

    // 2) per-bucket scans + private scatter + bucket sort (writes off, sc)
    scan2d_kernel<<<NB, 256, 0, stream>>>(hist2d, base2d, btot, NBLK, NB);
    bscan_kernel<<<1, 256, 0, stream>>>(btot, bbase, NB);
    scatter2d_kernel<<<NBLK, 256, 0, stream>>>(rows, cols, base2d, bbase,
                                               tmp, E, NB);
    bucket_sort_kernel<<<NB, 256, 0, stream>>>(tmp, bbase, btot, off, sc,
                                               N, E, NB);

    // 3) Atomic-free aggregation: one wave per node, shfl-fed gathers
    aggregate_kernel<<<((size_t)N * 64 + 255) / 256, 256, 0, stream>>>(
        off, sc, Q, KVP, out, N);
}

// Round 5
// 164.945 us; speedup vs baseline: 2.8376x; 1.0079x over previous
//
#include <hip/hip_runtime.h>
#include <math.h>

constexpr int D = 64;
constexpr int H = 4;
constexpr int EB = 8192;   // edges per binning block

// ---------------------------------------------------------------------------
// R24: (1) aggregate is VALU-issue-bound (R23: VALUBusy 71%, dur 44us) and
// half its agg_steps are fully-masked at deg~8 (always ran 4 steps/group).
// Now executes exactly nst=ceil(cnt/4) steps via unrolled quad/pair/single
// ladders (compile-time indices only); within a ladder only the final step
// needs a mask (earlier steps provably full).  deg=8: 2 steps not 4.
// (2) qkv: 48KB Wf LDS staging amortized 4x — each block now covers 256
// nodes (wave loops over 4 16-node tiles), 391 blocks instead of 1563.
// R23: shfl-fed gathers, consolidated 6-dispatch sort.  R22: contention-
// free 2-level counting sort.  R20: lane=dim-quad d=l&15, slot es=l>>4.
// Layouts (verified learn_hip m89/m120): A[m=lane&15][k=(lane>>4)*8+j],
// B[k=(lane>>4)*8+j][n=lane&15], C/D col=lane&15 row=(lane>>4)*4+reg.
// ---------------------------------------------------------------------------

typedef __attribute__((ext_vector_type(8))) short bf16x8;
typedef __attribute__((ext_vector_type(4))) float f32x4;

__device__ __forceinline__ unsigned short f32_to_bf16(float f) {
    const unsigned int u = __float_as_uint(f);
    return (unsigned short)((u + 0x7FFFu + ((u >> 16) & 1u)) >> 16);  // RNE
}
__device__ __forceinline__ float bf16_to_f32(unsigned short h) {
    return __uint_as_float(((unsigned int)h) << 16);
}
__device__ __forceinline__ float bf16lo_f32(unsigned int w) {   // bits 0-15
    return __uint_as_float(w << 16);
}
__device__ __forceinline__ float bf16hi_f32(unsigned int w) {   // bits 16-31
    return __uint_as_float(w & 0xFFFF0000u);
}

// ---------------------------------------------------------------------------
// Kernel 0: pre-split W into hi/lo MFMA B-fragment order with PERMUTED column
// map: fragment (mt, ct, ks, lane l, j) <- W_mt[ks*32+(l>>4)*8+j][4*(l&15)+ct]
// so MFMA acc[mt][ct] at lane m holds ORIGINAL output col 4m+ct.
// ---------------------------------------------------------------------------
__global__ __launch_bounds__(256) void prep_w_kernel(
    const float* __restrict__ Wq, const float* __restrict__ Wk,
    const float* __restrict__ Wv,
    unsigned short* __restrict__ WfH, unsigned short* __restrict__ WfL) {
    const float* W[3] = {Wq, Wk, Wv};
    for (int idx = blockIdx.x * 256 + threadIdx.x; idx < 3 * 4 * 2 * 64 * 8;
         idx += gridDim.x * 256) {
        const int j  = idx & 7;
        const int l  = (idx >> 3) & 63;
        const int ks = (idx >> 9) & 1;
        const int ct = (idx >> 10) & 3;
        const int mt = idx >> 12;
        const int krow = ks * 32 + (l >> 4) * 8 + j;
        const int col  = 4 * (l & 15) + ct;          // permuted column map
        const float w  = W[mt][krow * 64 + col];
        const unsigned short h = f32_to_bf16(w);
        WfH[idx] = h;
        WfL[idx] = f32_to_bf16(w - bf16_to_f32(h));
    }
}

// ---------------------------------------------------------------------------
// Kernel 1 (fused): blocks [0,HB) = bin_hist (LDS-only bucket histogram);
// blocks [HB,HB+QB) = QKV projection, 256 nodes/block (4 tiles per wave).
// ---------------------------------------------------------------------------
__global__ __launch_bounds__(256) void fused_qkv_hist_kernel(
    const float* __restrict__ emb,
    const unsigned short* __restrict__ WfH,
    const unsigned short* __restrict__ WfL,
    int N, float* __restrict__ Q, unsigned int* __restrict__ KVP,
    const int* __restrict__ rows, int* __restrict__ hist2d,
    int E, int NB, int HB) {
    __shared__ unsigned short sH[12288];   // 24 KB
    __shared__ unsigned short sL[12288];   // 24 KB
    __shared__ int h[512];                 // 2 KB (bin_hist part)
    const int tid = threadIdx.x;

    if ((int)blockIdx.x < HB) {
        // ---- bin_hist: per-block LDS histogram over 256-node buckets ----
        const int blk = blockIdx.x;
        for (int b = tid; b < NB; b += 256) h[b] = 0;
        __syncthreads();
        const int e0 = blk * EB;
        const int e1 = min(E, e0 + EB);
        for (int i = e0 + tid; i < e1; i += 256)
            atomicAdd(&h[rows[i] >> 8], 1);            // LDS, contention ~21
        __syncthreads();
        for (int b = tid; b < NB; b += 256) hist2d[blk * NB + b] = h[b];
        return;
    }

    // ---- qkv ----
    const int bx = blockIdx.x - HB;
    {
        const uint4* gh = (const uint4*)WfH;
        const uint4* gl = (const uint4*)WfL;
        uint4* shh = (uint4*)sH;
        uint4* sll = (uint4*)sL;
        for (int k = tid; k < 1536; k += 256) {
            shh[k] = gh[k];
            sll[k] = gl[k];
        }
    }
    __syncthreads();

    const int wv = tid >> 6;
    const int l  = tid & 63;
    const int qd = l >> 4;              // quad 0..3
    const int m  = l & 15;

    for (int tile = 0; tile < 4; ++tile) {
        const int n0 = bx * 256 + tile * 64 + wv * 16;
        if (n0 >= N) break;

        // A fragments, split hi/lo: k = ks*32 + qd*8 + j
        bf16x8 aH[2], aL[2];
        {
            int node = n0 + m;
            if (node >= N) node = N - 1;
            const float4* ep = (const float4*)(emb + (size_t)node * 64);
#pragma unroll
            for (int ks = 0; ks < 2; ++ks) {
                const float4 a0 = ep[ks * 8 + qd * 2 + 0];
                const float4 a1 = ep[ks * 8 + qd * 2 + 1];
                const float f[8] = {a0.x, a0.y, a0.z, a0.w,
                                    a1.x, a1.y, a1.z, a1.w};
                bf16x8 fh, fl;
#pragma unroll
                for (int j = 0; j < 8; ++j) {
                    const unsigned short hh = f32_to_bf16(f[j]);
                    fh[j] = (short)hh;
                    fl[j] = (short)f32_to_bf16(f[j] - bf16_to_f32(hh));
                }
                aH[ks] = fh;
                aL[ks] = fl;
            }
        }

        f32x4 acc[3][4];
#pragma unroll
        for (int mt = 0; mt < 3; ++mt)
#pragma unroll
            for (int ct = 0; ct < 4; ++ct)
                acc[mt][ct] = (f32x4){0.f, 0.f, 0.f, 0.f};

#pragma unroll
        for (int mt = 0; mt < 3; ++mt) {
#pragma unroll
            for (int ct = 0; ct < 4; ++ct) {
#pragma unroll
                for (int ks = 0; ks < 2; ++ks) {
                    const int fi = (((mt * 4 + ct) * 2 + ks) * 64 + l) * 8;
                    bf16x8 bh = *(const bf16x8*)&sH[fi];
                    bf16x8 bl = *(const bf16x8*)&sL[fi];
                    acc[mt][ct] = __builtin_amdgcn_mfma_f32_16x16x32_bf16(
                        aH[ks], bh, acc[mt][ct], 0, 0, 0);
                    acc[mt][ct] = __builtin_amdgcn_mfma_f32_16x16x32_bf16(
                        aH[ks], bl, acc[mt][ct], 0, 0, 0);
                    acc[mt][ct] = __builtin_amdgcn_mfma_f32_16x16x32_bf16(
                        aL[ks], bh, acc[mt][ct], 0, 0, 0);
                }
            }
        }

        // Epilogue: lane holds original cols 4m+ct (ct=0..3), row = qd*4+r.
#pragma unroll
        for (int r = 0; r < 4; ++r) {
            const int node = n0 + qd * 4 + r;
            if (node < N) {
                float4 oq;
                oq.x = acc[0][0][r]; oq.y = acc[0][1][r];
                oq.z = acc[0][2][r]; oq.w = acc[0][3][r];
                *(float4*)(Q + (size_t)node * 64 + 4 * m) = oq;

                uint4 kv;   // {kpack(4m,4m+1), vpack, kpack(4m+2,4m+3), vpack}
                kv.x = (unsigned int)f32_to_bf16(acc[1][0][r]) |
                       ((unsigned int)f32_to_bf16(acc[1][1][r]) << 16);
                kv.y = (unsigned int)f32_to_bf16(acc[2][0][r]) |
                       ((unsigned int)f32_to_bf16(acc[2][1][r]) << 16);
                kv.z = (unsigned int)f32_to_bf16(acc[1][2][r]) |
                       ((unsigned int)f32_to_bf16(acc[1][3][r]) << 16);
                kv.w = (unsigned int)f32_to_bf16(acc[2][2][r]) |
                       ((unsigned int)f32_to_bf16(acc[2][3][r]) << 16);
                *(uint4*)(KVP + (size_t)node * 64 + 4 * m) = kv;
            }
        }
    }
}

// Per-bucket exclusive scan over binning blocks (column b of hist2d).
// base2d[blk][b] = prefix within bucket (WITHOUT bucket base); btot[b]=total.
__global__ __launch_bounds__(256) void scan2d_kernel(
    const int* __restrict__ hist2d, int* __restrict__ base2d,
    int* __restrict__ btot, int NBLK, int NB) {
    __shared__ int s[256];
    const int b   = blockIdx.x;
    const int tid = threadIdx.x;
    const int x = (tid < NBLK) ? hist2d[tid * NB + b] : 0;
    s[tid] = x;
    __syncthreads();
    for (int o = 1; o < 256; o <<= 1) {
        int v = 0;
        if (tid >= o) v = s[tid - o];
        __syncthreads();
        if (tid >= o) s[tid] += v;
        __syncthreads();
    }
    if (tid < NBLK) base2d[tid * NB + b] = s[tid] - x;
    if (tid == 255) btot[b] = s[255];
}

// Exclusive scan of the NB bucket totals (1 block, chunked).
__global__ __launch_bounds__(256) void bscan_kernel(
    const int* __restrict__ btot, int* __restrict__ bbase, int NB) {
    __shared__ int s[256];
    __shared__ int carry;
    const int tid = threadIdx.x;
    if (tid == 0) carry = 0;
    __syncthreads();
    for (int base = 0; base < NB; base += 256) {
        const int i = base + tid;
        const int x = (i < NB) ? btot[i] : 0;
        s[tid] = x;
        __syncthreads();
        for (int o = 1; o < 256; o <<= 1) {
            int v = 0;
            if (tid >= o) v = s[tid - o];
            __syncthreads();
            if (tid >= o) s[tid] += v;
            __syncthreads();
        }
        if (i < NB) bbase[i] = carry + s[tid] - x;
        __syncthreads();
        if (tid == 255) carry += s[255];
        __syncthreads();
    }
}

// Phase A: each block places its edges into PRIVATE per-bucket sub-ranges
// via LDS cursors -> zero global atomics, contiguous write runs.
__global__ __launch_bounds__(256) void scatter2d_kernel(
    const int* __restrict__ rows, const int* __restrict__ cols,
    const int* __restrict__ base2d, const int* __restrict__ bbase,
    unsigned int* __restrict__ tmp, int E, int NB) {
    __shared__ int lcur[512];
    const int tid = threadIdx.x;
    const int blk = blockIdx.x;
    for (int b = tid; b < NB; b += 256)
        lcur[b] = bbase[b] + base2d[blk * NB + b];
    __syncthreads();
    const int e0 = blk * EB;
    const int e1 = min(E, e0 + EB);
    for (int i = e0 + tid; i < e1; i += 256) {
        const int r = rows[i];
        const int c = cols[i];
        const int p = atomicAdd(&lcur[r >> 8], 1);   // LDS atomic
        tmp[p] = ((unsigned int)(r & 255) << 24) | (unsigned int)c;
    }
}

// Phase B: block per bucket.  Self-contained: LDS histogram of the bucket's
// edges -> per-node offsets (writes off[]) -> LDS placement -> coalesced sc.
__global__ __launch_bounds__(256) void bucket_sort_kernel(
    const unsigned int* __restrict__ tmp, const int* __restrict__ bbase,
    const int* __restrict__ btot, int* __restrict__ off,
    int* __restrict__ sc, int N, int E, int NB) {
    __shared__ unsigned int ebuf[4096];   // 16 KB
    __shared__ int sbuf[4096];            // 16 KB
    __shared__ int lhist[256];
    __shared__ int s[256];
    __shared__ int lcur[256];
    const int b     = blockIdx.x;
    const int tid   = threadIdx.x;
    const int n0    = b * 256;
    const int gbase = bbase[b];
    const int cnt_b = btot[b];

    lhist[tid] = 0;
    __syncthreads();

    if (cnt_b <= 4096) {
        for (int i = tid; i < cnt_b; i += 256) {
            const unsigned int w = tmp[gbase + i];
            ebuf[i] = w;
            atomicAdd(&lhist[w >> 24], 1);            // LDS, contention ~8
        }
        __syncthreads();
        // exclusive scan of lhist
        const int x = lhist[tid];
        s[tid] = x;
        __syncthreads();
        for (int o = 1; o < 256; o <<= 1) {
            int v = 0;
            if (tid >= o) v = s[tid - o];
            __syncthreads();
            if (tid >= o) s[tid] += v;
            __syncthreads();
        }
        const int excl = s[tid] - x;
        const int node = n0 + tid;
        if (node < N) off[node] = gbase + excl;
        if (b == NB - 1 && tid == 0) off[N] = E;
        lcur[tid] = excl;
        __syncthreads();
        for (int i = tid; i < cnt_b; i += 256) {
            const unsigned int w = ebuf[i];
            const int p = atomicAdd(&lcur[w >> 24], 1);
            sbuf[p] = (int)(w & 0x00FFFFFFu);
        }
        __syncthreads();
        for (int i = tid; i < cnt_b; i += 256) sc[gbase + i] = sbuf[i];
    } else {
        // Fallback (never expected at E/N=8): direct global placement.
        for (int i = tid; i < cnt_b; i += 256)
            atomicAdd(&lhist[tmp[gbase + i] >> 24], 1);
        __syncthreads();
        const int x = lhist[tid];
        s[tid] = x;
        __syncthreads();
        for (int o = 1; o < 256; o <<= 1) {
            int v = 0;
            if (tid >= o) v = s[tid - o];
            __syncthreads();
            if (tid >= o) s[tid] += v;
            __syncthreads();
        }
        const int excl = s[tid] - x;
        const int node = n0 + tid;
        if (node < N) off[node] = gbase + excl;
        if (b == NB - 1 && tid == 0) off[N] = E;
        lcur[tid] = excl;
        __syncthreads();
        for (int i = tid; i < cnt_b; i += 256) {
            const unsigned int w = tmp[gbase + i];
            const int p = atomicAdd(&lcur[w >> 24], 1);
            sc[gbase + p] = (int)(w & 0x00FFFFFFu);
        }
    }
}

// ---------------------------------------------------------------------------
// Kernel 2: atomic-free aggregation.  lane l: d=l&15 (dim quad, one uint4 of
// KVP), es=l>>4 (edge slot).  Executes exactly nst=ceil(cnt/4) steps via
// unrolled quad/pair/single ladders; in each ladder only the LAST step can
// be partial (earlier steps provably full since (nst-1)*4 < cnt).
// ---------------------------------------------------------------------------
__device__ __forceinline__ void agg_step(const uint4 kv, const float4 q4,
                                         bool ok, float& aN, float& a0,
                                         float& a1, float& a2, float& a3) {
    float pp = q4.x * bf16lo_f32(kv.x);
    pp = fmaf(q4.y, bf16hi_f32(kv.x), pp);
    pp = fmaf(q4.z, bf16lo_f32(kv.z), pp);
    pp = fmaf(q4.w, bf16hi_f32(kv.z), pp);
    pp += __shfl_xor(pp, 1);
    pp += __shfl_xor(pp, 2);
    float e = __expf(fminf(fmaxf(pp, -10.f), 10.f));
    e = ok ? e : 0.f;
    aN += e;
    a0 = fmaf(e, bf16lo_f32(kv.y), a0);
    a1 = fmaf(e, bf16hi_f32(kv.y), a1);
    a2 = fmaf(e, bf16lo_f32(kv.w), a2);
    a3 = fmaf(e, bf16hi_f32(kv.w), a3);
}

__global__ __launch_bounds__(256) void aggregate_kernel(
    const int* __restrict__ off, const int* __restrict__ sc,
    const float* __restrict__ Q, const unsigned int* __restrict__ KVP,
    float* __restrict__ out, int N) {
    const int t = blockIdx.x * 256 + threadIdx.x;
    const int n = t >> 6;
    const int l = t & 63;
    if (n >= N) return;
    const int d  = l & 15;              // dim quad
    const int es = l >> 4;              // edge slot 0..3

    const int off0 = off[n];
    const int off1 = off[n + 1];
    const int deg  = off1 - off0;
    const float4 q4 = *(const float4*)(Q + (size_t)n * 64 + 4 * d);

    float aN = 0.f, a0 = 0.f, a1 = 0.f, a2 = 0.f, a3 = 0.f;

    for (int base = 0; base < deg; base += 64) {
        const int cnt = min(64, deg - base);
        int myc = 0;
        if (l < cnt) myc = sc[off0 + base + l];   // coalesced, 1 wave-load
        const int nst = (cnt + 3) >> 2;           // 4-edge steps needed
        int si = 0;
        // Quad ladder: steps si..si+3 (only step si+3 can be partial).
        for (; si + 4 <= nst; si += 4) {
            const int e0 = si * 4 + es;
            const bool ok3 = e0 + 12 < cnt;
            const int c0 = __shfl(myc, e0);
            const int c1 = __shfl(myc, e0 + 4);
            const int c2 = __shfl(myc, e0 + 8);
            const int c3 = __shfl(myc, ok3 ? e0 + 12 : 0);
            const uint4 kv0 = *(const uint4*)(KVP + (size_t)c0 * 64 + 4 * d);
            const uint4 kv1 = *(const uint4*)(KVP + (size_t)c1 * 64 + 4 * d);
            const uint4 kv2 = *(const uint4*)(KVP + (size_t)c2 * 64 + 4 * d);
            const uint4 kv3 = *(const uint4*)(KVP + (size_t)c3 * 64 + 4 * d);
            agg_step(kv0, q4, true, aN, a0, a1, a2, a3);
            agg_step(kv1, q4, true, aN, a0, a1, a2, a3);
            agg_step(kv2, q4, true, aN, a0, a1, a2, a3);
            agg_step(kv3, q4, ok3, aN, a0, a1, a2, a3);
        }
        // Pair ladder: steps si, si+1 (only si+1 can be partial).
        if (si + 2 <= nst) {
            const int e0 = si * 4 + es;
            const bool ok1 = e0 + 4 < cnt;
            const int c0 = __shfl(myc, e0);
            const int c1 = __shfl(myc, ok1 ? e0 + 4 : 0);
            const uint4 kv0 = *(const uint4*)(KVP + (size_t)c0 * 64 + 4 * d);
            const uint4 kv1 = *(const uint4*)(KVP + (size_t)c1 * 64 + 4 * d);
            agg_step(kv0, q4, true, aN, a0, a1, a2, a3);
            agg_step(kv1, q4, ok1, aN, a0, a1, a2, a3);
            si += 2;
        }
        // Single (possibly partial) step.
        if (si < nst) {
            const int e0 = si * 4 + es;
            const bool ok0 = e0 < cnt;
            const int c0 = __shfl(myc, ok0 ? e0 : 0);
            const uint4 kv0 = *(const uint4*)(KVP + (size_t)c0 * 64 + 4 * d);
            agg_step(kv0, q4, ok0, aN, a0, a1, a2, a3);
        }
    }

    // Combine the four edge slots.
    aN += __shfl_xor(aN, 16);  aN += __shfl_xor(aN, 32);
    a0 += __shfl_xor(a0, 16);  a0 += __shfl_xor(a0, 32);
    a1 += __shfl_xor(a1, 16);  a1 += __shfl_xor(a1, 32);
    a2 += __shfl_xor(a2, 16);  a2 += __shfl_xor(a2, 32);
    a3 += __shfl_xor(a3, 16);  a3 += __shfl_xor(a3, 32);

    if (l < 16) {
        const float inv = 1.f / (aN + 1e-8f);
        float4 o;
        o.x = a0 * inv;
        o.y = a1 * inv;
        o.z = a2 * inv;
        o.w = a3 * inv;
        *(float4*)(out + (size_t)n * 64 + 4 * d) = o;
    }
}

extern "C" void kernel_launch(void* const* d_in, const int* in_sizes, int n_in,
                              void* d_out, int out_size, void* d_ws, size_t ws_size,
                              hipStream_t stream) {
    const float* emb = (const float*)d_in[0];
    const float* Wq  = (const float*)d_in[1];
    const float* Wk  = (const float*)d_in[2];
    const float* Wv  = (const float*)d_in[3];
    const int*   w32 = (const int*)d_in[4];

    const int N    = in_sizes[0] / D;   // 100000
    const int E    = in_sizes[4] / 2;   // 800000
    const int NB   = (N + 255) / 256;   // 391 buckets
    const int NBLK = (E + EB - 1) / EB; // 98 binning blocks
    const int QB   = (N + 255) / 256;   // 391 qkv blocks (256 nodes each)
    const size_t ND = (size_t)N * D;

    const int* rows = w32;            // validated r10: [2,E], rows = half 0
    const int* cols = w32 + E;

    // Workspace: WfH | WfL | Q f32 | KVP | off | sc | tmp | hist2d | base2d |
    // btot | bbase   (~58 MB)
    unsigned short* WfH = (unsigned short*)d_ws;           // 24 KB
    unsigned short* WfL = WfH + 12288;                     // 24 KB
    float*          Q   = (float*)(WfL + 12288);
    unsigned int*   KVP = (unsigned int*)(Q + ND);
    int*   off  = (int*)(KVP + ND);   // N+1
    int*   sc   = off + N + 2;
    unsigned int* tmp = (unsigned int*)(sc + E);
    int*   hist2d = (int*)(tmp + E);  // NBLK*NB
    int*   base2d = hist2d + NBLK * NB;
    int*   btot   = base2d + NBLK * NB;
    int*   bbase  = btot + NB;

    float* out = (float*)d_out;

    // 0) W -> hi/lo MFMA fragment order
    prep_w_kernel<<<48, 256, 0, stream>>>(Wq, Wk, Wv, WfH, WfL);

    // 1) fused: bin_hist (blocks [0,NBLK)) + QKV (blocks [NBLK,NBLK+QB))
    fused_qkv_hist_kernel<<<NBLK + QB, 256, 0, stream>>>(
        emb, WfH, WfL, N, Q, KVP, rows, hist2d, E, NB, NBLK);

    // 2) per-bucket scans + private scatter + bucket sort (writes off, sc)
    scan2d_kernel<<<NB, 256, 0, stream>>>(hist2d, base2d, btot, NBLK, NB);
    bscan_kernel<<<1, 256, 0, stream>>>(btot, bbase, NB);
    scatter2d_kernel<<<NBLK, 256, 0, stream>>>(rows, cols, base2d, bbase,
                                               tmp, E, NB);
    bucket_sort_kernel<<<NB, 256, 0, stream>>>(tmp, bbase, btot, off, sc,
                                               N, E, NB);

    // 3) Atomic-free aggregation: one wave per node, step-count-exact
    aggregate_kernel<<<((size_t)N * 64 + 255) / 256, 256, 0, stream>>>(
        off, sc, Q, KVP, out, N);
}